// Round 5
// baseline (145.886 us; speedup 1.0000x reference)
//
#include <hip/hip_runtime.h>
#include <math.h>

#define NN 2048
#define DD 64
#define HH 64

// ---------------------------------------------------------------------------
// Stage 1 (unchanged, passing): u[i][h] = z[i]·Wa[h] + b1[h]; v[i][h] = z[i]·Wb[h]
// ---------------------------------------------------------------------------
__global__ __launch_bounds__(256) void prep_kernel(
    const float* __restrict__ z, const float* __restrict__ W1,
    const float* __restrict__ b1, float* __restrict__ u, float* __restrict__ v) {
  __shared__ float zs[8 * DD];
  const int t = threadIdx.x;
  const int i0 = blockIdx.x * 8;
  if (t < 128) {
    reinterpret_cast<float4*>(zs)[t] =
        reinterpret_cast<const float4*>(z + (size_t)i0 * DD)[t];
  }
  __syncthreads();

  const int hs = t & 127;
  const int rg = t >> 7;
  const int h = hs & 63;
  const int side = hs >> 6;
  const float* wrow = W1 + h * (2 * DD) + side * DD;

  float acc0 = 0.f, acc1 = 0.f, acc2 = 0.f, acc3 = 0.f;
#pragma unroll
  for (int d4 = 0; d4 < DD / 4; ++d4) {
    const float4 wv = reinterpret_cast<const float4*>(wrow)[d4];
    const float* z0 = zs + (rg * 4 + 0) * DD + d4 * 4;
    const float* z1 = z0 + DD;
    const float* z2 = z1 + DD;
    const float* z3 = z2 + DD;
    acc0 = fmaf(z0[3], wv.w, fmaf(z0[2], wv.z, fmaf(z0[1], wv.y, fmaf(z0[0], wv.x, acc0))));
    acc1 = fmaf(z1[3], wv.w, fmaf(z1[2], wv.z, fmaf(z1[1], wv.y, fmaf(z1[0], wv.x, acc1))));
    acc2 = fmaf(z2[3], wv.w, fmaf(z2[2], wv.z, fmaf(z2[1], wv.y, fmaf(z2[0], wv.x, acc2))));
    acc3 = fmaf(z3[3], wv.w, fmaf(z3[2], wv.z, fmaf(z3[1], wv.y, fmaf(z3[0], wv.x, acc3))));
  }
  const float bias = side ? 0.0f : b1[h];
  float* dst = side ? v : u;
  const int ib = i0 + rg * 4;
  dst[(size_t)(ib + 0) * HH + h] = acc0 + bias;
  dst[(size_t)(ib + 1) * HH + h] = acc1 + bias;
  dst[(size_t)(ib + 2) * HH + h] = acc2 + bias;
  dst[(size_t)(ib + 3) * HH + h] = acc3 + bias;
}

// ---------------------------------------------------------------------------
// Stage 1.5: vt[h][i] = v[i][h] (transpose, for uniform s_load rows in pair),
//            a[i] = 0.5*sum_h W2[h]*u[i][h], b[i] = 0.5*sum_h W2[h]*v[i][h]
// ---------------------------------------------------------------------------
__global__ __launch_bounds__(256) void prep2_kernel(
    const float* __restrict__ u, const float* __restrict__ v,
    const float* __restrict__ W2,
    float* __restrict__ vt, float* __restrict__ a, float* __restrict__ b) {
  __shared__ float lu[64][65];
  __shared__ float lv[64][65];
  const int t = threadIdx.x;
  const int i0 = blockIdx.x * 64;

#pragma unroll
  for (int k = 0; k < 4; ++k) {
    const int idx = t + k * 256;       // 1024 float4 chunks per tile
    const int row = idx >> 4;
    const int c4 = idx & 15;
    const float4 fu = *reinterpret_cast<const float4*>(u + (size_t)(i0 + row) * HH + c4 * 4);
    const float4 fv = *reinterpret_cast<const float4*>(v + (size_t)(i0 + row) * HH + c4 * 4);
    lu[row][c4 * 4 + 0] = fu.x; lu[row][c4 * 4 + 1] = fu.y;
    lu[row][c4 * 4 + 2] = fu.z; lu[row][c4 * 4 + 3] = fu.w;
    lv[row][c4 * 4 + 0] = fv.x; lv[row][c4 * 4 + 1] = fv.y;
    lv[row][c4 * 4 + 2] = fv.z; lv[row][c4 * 4 + 3] = fv.w;
  }
  __syncthreads();

  // vt write: coalesced float4 along i
#pragma unroll
  for (int k = 0; k < 4; ++k) {
    const int idx = t + k * 256;
    const int h = idx >> 4;
    const int c4 = idx & 15;
    const float4 o = make_float4(lv[c4 * 4 + 0][h], lv[c4 * 4 + 1][h],
                                 lv[c4 * 4 + 2][h], lv[c4 * 4 + 3][h]);
    *reinterpret_cast<float4*>(vt + (size_t)h * NN + i0 + c4 * 4) = o;
  }

  // a, b: 4 threads per row, 16 h each, shuffle-reduce
  {
    const int r = t >> 2;
    const int qd = t & 3;
    float sa = 0.f, sb = 0.f;
#pragma unroll
    for (int k = 0; k < 16; ++k) {
      const int h = qd * 16 + k;
      const float w = W2[h];
      sa = fmaf(w, lu[r][h], sa);
      sb = fmaf(w, lv[r][h], sb);
    }
    sa += __shfl_xor(sa, 1); sa += __shfl_xor(sa, 2);
    sb += __shfl_xor(sb, 1); sb += __shfl_xor(sb, 2);
    if (qd == 0) {
      a[i0 + r] = 0.5f * sa;
      b[i0 + r] = 0.5f * sb;
    }
  }
}

// ---------------------------------------------------------------------------
// Stage 2: out[i][j] = sigmoid(a[i] + b[j] + b2 + 0.5*sum_h W2[h]*|u[i,h]+v[j,h]|)
// with the diagonal zeroed. One lane per output row; u-row in 64 VGPRs;
// v/W2 fetched via wave-uniform s_loads. 2 VALU ops per (i,j,h), no LDS.
// ---------------------------------------------------------------------------
__global__ __launch_bounds__(128) void pair_kernel(
    const float* __restrict__ u, const float* __restrict__ vt,
    const float* __restrict__ a, const float* __restrict__ b,
    const float* __restrict__ W2, const float* __restrict__ b2,
    float* __restrict__ out) {
  const int t = threadIdx.x;
  const int i = blockIdx.y * 128 + t;
  const int jbase = blockIdx.x * 64;

  // u row -> 64 registers
  float p[64];
  const float4* urow = reinterpret_cast<const float4*>(u + (size_t)i * HH);
#pragma unroll
  for (int k = 0; k < 16; ++k) {
    const float4 f = urow[k];
    p[4 * k + 0] = f.x; p[4 * k + 1] = f.y;
    p[4 * k + 2] = f.z; p[4 * k + 3] = f.w;
  }
  const float ai = a[i];
  const float bias2 = b2[0];

  for (int s = 0; s < 4; ++s) {
    const int j0 = jbase + s * 16;
    float acc[16] = {};
#pragma unroll
    for (int h = 0; h < HH; ++h) {  // FULL unroll: p[h] stays in registers
      const float wh = W2[h];                                   // s_load
      const float* vr = vt + (size_t)h * NN + j0;               // uniform row
      const float4 q0 = *reinterpret_cast<const float4*>(vr);
      const float4 q1 = *reinterpret_cast<const float4*>(vr + 4);
      const float4 q2 = *reinterpret_cast<const float4*>(vr + 8);
      const float4 q3 = *reinterpret_cast<const float4*>(vr + 12);
      const float qq[16] = {q0.x, q0.y, q0.z, q0.w, q1.x, q1.y, q1.z, q1.w,
                            q2.x, q2.y, q2.z, q2.w, q3.x, q3.y, q3.z, q3.w};
#pragma unroll
      for (int c = 0; c < 16; ++c) {
        const float sm = p[h] + qq[c];           // v_add_f32 (sgpr + vgpr)
        acc[c] = fmaf(wh, fabsf(sm), acc[c]);    // v_fma_f32 with |.| modifier
      }
    }

    const float* br = b + j0;  // uniform -> s_load
    const float4 bj0 = *reinterpret_cast<const float4*>(br);
    const float4 bj1 = *reinterpret_cast<const float4*>(br + 4);
    const float4 bj2 = *reinterpret_cast<const float4*>(br + 8);
    const float4 bj3 = *reinterpret_cast<const float4*>(br + 12);
    const float bj[16] = {bj0.x, bj0.y, bj0.z, bj0.w, bj1.x, bj1.y, bj1.z, bj1.w,
                          bj2.x, bj2.y, bj2.z, bj2.w, bj3.x, bj3.y, bj3.z, bj3.w};

    float r[16];
#pragma unroll
    for (int c = 0; c < 16; ++c) {
      const float x = ai + bj[c] + bias2 + 0.5f * acc[c];
      const float sg = 1.0f / (1.0f + __expf(-x));
      r[c] = (i == j0 + c) ? 0.0f : sg;
    }
    float* orow = out + (size_t)i * NN + j0;
#pragma unroll
    for (int c4 = 0; c4 < 4; ++c4) {
      *reinterpret_cast<float4*>(orow + c4 * 4) =
          make_float4(r[c4 * 4 + 0], r[c4 * 4 + 1], r[c4 * 4 + 2], r[c4 * 4 + 3]);
    }
  }
}

extern "C" void kernel_launch(void* const* d_in, const int* in_sizes, int n_in,
                              void* d_out, int out_size, void* d_ws, size_t ws_size,
                              hipStream_t stream) {
  const float* z  = (const float*)d_in[0];
  const float* W1 = (const float*)d_in[1];
  const float* b1 = (const float*)d_in[2];
  const float* W2 = (const float*)d_in[3];
  const float* b2 = (const float*)d_in[4];
  float* out = (float*)d_out;

  float* u  = (float*)d_ws;                    // [2048][64]  512 KB
  float* v  = u + (size_t)NN * HH;             // [2048][64]  512 KB
  float* vt = v + (size_t)NN * HH;             // [64][2048]  512 KB
  float* a  = vt + (size_t)NN * HH;            // [2048]      8 KB
  float* b  = a + NN;                          // [2048]      8 KB

  prep_kernel<<<NN / 8, 256, 0, stream>>>(z, W1, b1, u, v);
  prep2_kernel<<<NN / 64, 256, 0, stream>>>(u, v, W2, vt, a, b);
  pair_kernel<<<dim3(NN / 64, NN / 128), 128, 0, stream>>>(u, vt, a, b, W2, b2, out);
}

// Round 7
// 92.390 us; speedup vs baseline: 1.5790x; 1.5790x over previous
//
#include <hip/hip_runtime.h>
#include <math.h>

#define NN 2048
#define DD 64
#define HH 64
#define TILE 128
#define TP (TILE + 4)  // padded LDS row: kills 16-way bank conflict on transposed staging writes

// ---------------------------------------------------------------------------
// Stage 1: u[i][h] = z[i]·Wa[h] + b1[h]; v[i][h] = z[i]·Wb[h]
// Plus fused rank-1 terms: a[i] = 0.5*sum_h W2[h]*u[i][h], b[i] = same on v.
// Each wave spans h=0..63 for fixed (side, row-group) -> wave shuffle-reduce.
// ---------------------------------------------------------------------------
__global__ __launch_bounds__(256) void prep_kernel(
    const float* __restrict__ z, const float* __restrict__ W1,
    const float* __restrict__ b1, const float* __restrict__ W2,
    float* __restrict__ u, float* __restrict__ v,
    float* __restrict__ a, float* __restrict__ b) {
  __shared__ float zs[8 * DD];
  const int t = threadIdx.x;
  const int i0 = blockIdx.x * 8;
  if (t < 128) {
    reinterpret_cast<float4*>(zs)[t] =
        reinterpret_cast<const float4*>(z + (size_t)i0 * DD)[t];
  }
  __syncthreads();

  const int hs = t & 127;
  const int rg = t >> 7;
  const int h = hs & 63;
  const int side = hs >> 6;
  const float* wrow = W1 + h * (2 * DD) + side * DD;

  float acc0 = 0.f, acc1 = 0.f, acc2 = 0.f, acc3 = 0.f;
#pragma unroll
  for (int d4 = 0; d4 < DD / 4; ++d4) {
    const float4 wv = reinterpret_cast<const float4*>(wrow)[d4];
    const float* z0 = zs + (rg * 4 + 0) * DD + d4 * 4;
    const float* z1 = z0 + DD;
    const float* z2 = z1 + DD;
    const float* z3 = z2 + DD;
    acc0 = fmaf(z0[3], wv.w, fmaf(z0[2], wv.z, fmaf(z0[1], wv.y, fmaf(z0[0], wv.x, acc0))));
    acc1 = fmaf(z1[3], wv.w, fmaf(z1[2], wv.z, fmaf(z1[1], wv.y, fmaf(z1[0], wv.x, acc1))));
    acc2 = fmaf(z2[3], wv.w, fmaf(z2[2], wv.z, fmaf(z2[1], wv.y, fmaf(z2[0], wv.x, acc2))));
    acc3 = fmaf(z3[3], wv.w, fmaf(z3[2], wv.z, fmaf(z3[1], wv.y, fmaf(z3[0], wv.x, acc3))));
  }
  const float bias = side ? 0.0f : b1[h];
  const float s0 = acc0 + bias, s1 = acc1 + bias, s2 = acc2 + bias, s3 = acc3 + bias;
  float* dst = side ? v : u;
  const int ib = i0 + rg * 4;
  dst[(size_t)(ib + 0) * HH + h] = s0;
  dst[(size_t)(ib + 1) * HH + h] = s1;
  dst[(size_t)(ib + 2) * HH + h] = s2;
  dst[(size_t)(ib + 3) * HH + h] = s3;

  // rank-1 terms: wave holds h=0..63 in its 64 lanes (h == t&63 within wave)
  const float wh = W2[h];
  float r0 = wh * s0, r1 = wh * s1, r2 = wh * s2, r3 = wh * s3;
#pragma unroll
  for (int m = 1; m < 64; m <<= 1) {
    r0 += __shfl_xor(r0, m);
    r1 += __shfl_xor(r1, m);
    r2 += __shfl_xor(r2, m);
    r3 += __shfl_xor(r3, m);
  }
  if ((t & 63) == 0) {
    float* d2 = side ? b : a;
    d2[ib + 0] = 0.5f * r0;
    d2[ib + 1] = 0.5f * r1;
    d2[ib + 2] = 0.5f * r2;
    d2[ib + 3] = 0.5f * r3;
  }
}

// ---------------------------------------------------------------------------
// Stage 2: out[i][j] = sigmoid(a[i]+b[j]+b2 + 0.5*sum_h W2[h]*|u[i,h]+v[j,h]|),
// diagonal zeroed.  relu(x)=(x+|x|)/2 -> 2 VALU ops per (i,j,h) via free abs
// modifier.  128x128 tile, 512 threads, 4x8 micro-tile -> acc[4][8]=32 VGPRs
// (no spill), LDS [h][i] transposed tiles, 3x ds_read_b128 per 64 VALU instrs.
// 256 blocks = 1/CU, 2 waves/SIMD.
// ---------------------------------------------------------------------------
__global__ __launch_bounds__(512, 2) void pair_kernel(
    const float* __restrict__ u, const float* __restrict__ v,
    const float* __restrict__ a, const float* __restrict__ b,
    const float* __restrict__ W2, const float* __restrict__ b2,
    float* __restrict__ out) {
  __shared__ float su[HH][TP];  // [h][i-local], ~33 KB
  __shared__ float sv[HH][TP];  // [h][j-local], ~33 KB

  const int t = threadIdx.x;
  const int i0 = blockIdx.y * TILE;
  const int j0 = blockIdx.x * TILE;

  // ---- staging with in-register 4x4 transpose: thread = (i/j-quad r, h-quad c)
  {
    const int r = t >> 4;  // 0..31
    const int c = t & 15;  // 0..15
    const float* us = u + (size_t)(i0 + 4 * r) * HH + 4 * c;
    const float4 a0 = *reinterpret_cast<const float4*>(us);
    const float4 a1 = *reinterpret_cast<const float4*>(us + HH);
    const float4 a2 = *reinterpret_cast<const float4*>(us + 2 * HH);
    const float4 a3 = *reinterpret_cast<const float4*>(us + 3 * HH);
    *reinterpret_cast<float4*>(&su[4 * c + 0][4 * r]) = make_float4(a0.x, a1.x, a2.x, a3.x);
    *reinterpret_cast<float4*>(&su[4 * c + 1][4 * r]) = make_float4(a0.y, a1.y, a2.y, a3.y);
    *reinterpret_cast<float4*>(&su[4 * c + 2][4 * r]) = make_float4(a0.z, a1.z, a2.z, a3.z);
    *reinterpret_cast<float4*>(&su[4 * c + 3][4 * r]) = make_float4(a0.w, a1.w, a2.w, a3.w);
    const float* vs = v + (size_t)(j0 + 4 * r) * HH + 4 * c;
    const float4 c0 = *reinterpret_cast<const float4*>(vs);
    const float4 c1 = *reinterpret_cast<const float4*>(vs + HH);
    const float4 c2 = *reinterpret_cast<const float4*>(vs + 2 * HH);
    const float4 c3 = *reinterpret_cast<const float4*>(vs + 3 * HH);
    *reinterpret_cast<float4*>(&sv[4 * c + 0][4 * r]) = make_float4(c0.x, c1.x, c2.x, c3.x);
    *reinterpret_cast<float4*>(&sv[4 * c + 1][4 * r]) = make_float4(c0.y, c1.y, c2.y, c3.y);
    *reinterpret_cast<float4*>(&sv[4 * c + 2][4 * r]) = make_float4(c0.z, c1.z, c2.z, c3.z);
    *reinterpret_cast<float4*>(&sv[4 * c + 3][4 * r]) = make_float4(c0.w, c1.w, c2.w, c3.w);
  }
  __syncthreads();

  const int tx = t & 15;  // j-octet: j = j0 + tx*8 + cc
  const int ty = t >> 4;  // i-quad:  i = i0 + ty*4 + k

  float acc[4][8] = {};
#pragma unroll 4
  for (int h = 0; h < HH; ++h) {
    const float wh = W2[h];  // wave-uniform -> SGPR
    const float4 ua = *reinterpret_cast<const float4*>(&su[h][ty * 4]);   // 4-unique/wave (broadcast)
    const float4 vb0 = *reinterpret_cast<const float4*>(&sv[h][tx * 8]);  // 16-unique/wave
    const float4 vb1 = *reinterpret_cast<const float4*>(&sv[h][tx * 8 + 4]);
    const float uav[4] = {ua.x, ua.y, ua.z, ua.w};
    const float vbv[8] = {vb0.x, vb0.y, vb0.z, vb0.w, vb1.x, vb1.y, vb1.z, vb1.w};
#pragma unroll
    for (int k = 0; k < 4; ++k) {
#pragma unroll
      for (int cc = 0; cc < 8; ++cc) {
        acc[k][cc] = fmaf(wh, fabsf(uav[k] + vbv[cc]), acc[k][cc]);  // add + fma(|.|)
      }
    }
  }

  const float bias2 = b2[0];
  const float4 bj0 = *reinterpret_cast<const float4*>(b + j0 + tx * 8);
  const float4 bj1 = *reinterpret_cast<const float4*>(b + j0 + tx * 8 + 4);
  const float bj[8] = {bj0.x, bj0.y, bj0.z, bj0.w, bj1.x, bj1.y, bj1.z, bj1.w};

#pragma unroll
  for (int k = 0; k < 4; ++k) {
    const int i = i0 + ty * 4 + k;
    const float ai = a[i];
    float r[8];
#pragma unroll
    for (int cc = 0; cc < 8; ++cc) {
      const float x = ai + bj[cc] + bias2 + 0.5f * acc[k][cc];
      const float sg = 1.0f / (1.0f + __expf(-x));
      r[cc] = (i == j0 + tx * 8 + cc) ? 0.0f : sg;
    }
    float* orow = out + (size_t)i * NN + j0 + tx * 8;
    *reinterpret_cast<float4*>(orow) = make_float4(r[0], r[1], r[2], r[3]);
    *reinterpret_cast<float4*>(orow + 4) = make_float4(r[4], r[5], r[6], r[7]);
  }
}

extern "C" void kernel_launch(void* const* d_in, const int* in_sizes, int n_in,
                              void* d_out, int out_size, void* d_ws, size_t ws_size,
                              hipStream_t stream) {
  const float* z  = (const float*)d_in[0];
  const float* W1 = (const float*)d_in[1];
  const float* b1 = (const float*)d_in[2];
  const float* W2 = (const float*)d_in[3];
  const float* b2 = (const float*)d_in[4];
  float* out = (float*)d_out;

  float* u = (float*)d_ws;               // [2048][64]  512 KB
  float* v = u + (size_t)NN * HH;        // [2048][64]  512 KB
  float* a = v + (size_t)NN * HH;        // [2048]      8 KB
  float* b = a + NN;                     // [2048]      8 KB

  prep_kernel<<<NN / 8, 256, 0, stream>>>(z, W1, b1, W2, u, v, a, b);
  pair_kernel<<<dim3(NN / TILE, NN / TILE), 512, 0, stream>>>(u, v, a, b, W2, b2, out);
}